// Round 6
// baseline (419.916 us; speedup 1.0000x reference)
//
#include <hip/hip_runtime.h>

#define NB 16
#define NT 4096
#define ND 512
#define NLEV 12

typedef float f4v __attribute__((ext_vector_type(4)));

// ---------- exact decision path (verified rounds 2-5): f32 diffs, exact f64 sum,
// ---------- round once to f32, compare vs 1024 (== 32^2, monotone w/ sqrtf>32).
__device__ __forceinline__ bool decide_exact(const float* __restrict__ base, int row,
                                             int lane, float4 r0, float4 r1) {
    const float4* fp = (const float4*)(base + (size_t)row * ND);
    float4 y0 = fp[lane];
    float4 y1 = fp[lane + 64];
    float d;
    double sd;
    d = r0.x - y0.x; sd  = (double)d * d;
    d = r0.y - y0.y; sd += (double)d * d;
    d = r0.z - y0.z; sd += (double)d * d;
    d = r0.w - y0.w; sd += (double)d * d;
    d = r1.x - y1.x; sd += (double)d * d;
    d = r1.y - y1.y; sd += (double)d * d;
    d = r1.z - y1.z; sd += (double)d * d;
    d = r1.w - y1.w; sd += (double)d * d;
    #pragma unroll
    for (int off = 32; off >= 1; off >>= 1) sd += __shfl_xor(sd, off, 64);
    return ((float)sd > 1024.0f);
}

// ---------------- Kernel A v6: wave per j, 8-lane group per probe, width-8 ----------
// 99.6% of j's resolve in ONE batch: 16 independent dwordx4 loads (one latency
// window), 64 FMA as 4 independent chains, 3 shuffle steps, one ballot.
__global__ __launch_bounds__(256) void kA_next(const float* __restrict__ in,
                                               int* __restrict__ nxt) {
    int wave = blockIdx.x * 4 + (threadIdx.x >> 6);   // 0..65535 = (b, j)
    int lane = threadIdx.x & 63;
    int b = wave >> 12;
    int j = wave & (NT - 1);
    int g = lane >> 3;    // probe group 0..7
    int q = lane & 7;     // lane within group

    const float* base = in + (size_t)b * NT * ND;
    const float4* jrow = (const float4*)(base + (size_t)j * ND);
    float4 rep[16];
    #pragma unroll
    for (int k = 0; k < 16; ++k) rep[k] = jrow[q + 8 * k];

    int result = NT;
    int i = j + 1;
    while (i < NT) {
        int row = i + g;
        bool valid = row < NT;
        int rc = valid ? row : NT - 1;
        const float4* pr = (const float4*)(base + (size_t)rc * ND);
        float4 acc = make_float4(0.f, 0.f, 0.f, 0.f);   // 4 independent FMA chains
        #pragma unroll
        for (int k = 0; k < 16; ++k) {
            float4 x = pr[q + 8 * k];
            float d;
            d = rep[k].x - x.x; acc.x = fmaf(d, d, acc.x);
            d = rep[k].y - x.y; acc.y = fmaf(d, d, acc.y);
            d = rep[k].z - x.z; acc.z = fmaf(d, d, acc.z);
            d = rep[k].w - x.w; acc.w = fmaf(d, d, acc.w);
        }
        float s = (acc.x + acc.y) + (acc.z + acc.w);
        // 8-lane group reduction: after xor 1,2,4 all 8 lanes hold the group sum
        s += __shfl_xor(s, 1, 64);
        s += __shfl_xor(s, 2, 64);
        s += __shfl_xor(s, 4, 64);

        unsigned long long ym = __ballot(valid && s > 1024.25f);
        unsigned long long am = __ballot(valid && s > 1023.75f && s <= 1024.25f);
        // group g's verdict = bit 8g (all 8 bits of a group are equal);
        // byte-LSB gather: packed bit g = source bit 8g.
        unsigned vy = (unsigned)(((ym & 0x0101010101010101ULL) * 0x0102040810204080ULL) >> 56);
        unsigned va = (unsigned)(((am & 0x0101010101010101ULL) * 0x0102040810204080ULL) >> 56);

        int found = -1;
        for (;;) {   // wave-uniform resolve in ascending probe order
            int gy = vy ? (__ffs(vy) - 1) : 8;
            int ga = va ? (__ffs(va) - 1) : 8;
            if (ga < gy) {
                float4 r0 = jrow[lane];        // rare path; L1-hot reload
                float4 r1 = jrow[lane + 64];
                if (decide_exact(base, i + ga, lane, r0, r1)) { found = i + ga; break; }
                va &= va - 1;
            } else {
                if (gy < 8) found = i + gy;
                break;
            }
        }
        if (found >= 0) { result = found; break; }
        i += 8;
    }
    if (lane == 0) nxt[b * NT + j] = result;
}

// ---------------- kChain: doubling + reach bitmap + ranks (verified r4/r5) --------
__global__ __launch_bounds__(1024) void kChain(const int* __restrict__ nxt,
                                               int* __restrict__ start,
                                               int* __restrict__ nseg,
                                               float* __restrict__ out_tail) {
    __shared__ unsigned short h[NT + 1];
    __shared__ unsigned short h2[NT + 1];
    __shared__ unsigned reach[NT / 32];
    __shared__ unsigned pref[NT / 32];
    __shared__ unsigned wsum[NT / 32];
    int b = blockIdx.x;
    int t = threadIdx.x;
    for (int j = t; j <= NT; j += 1024)
        h[j] = (j < NT) ? (unsigned short)nxt[b * NT + j] : (unsigned short)NT;
    for (int w = t; w < NT / 32; w += 1024) reach[w] = 0;
    __syncthreads();
    if (t == 0) reach[0] = 1u;
    __syncthreads();
    for (int k = 0; k < NLEV; ++k) {
        if (t < NT / 32) {
            unsigned m = reach[t];
            while (m) {
                int bit = __ffs(m) - 1; m &= m - 1;
                int d = h[t * 32 + bit];
                if (d < NT) atomicOr(&reach[d >> 5], 1u << (d & 31));
            }
        }
        __syncthreads();
        for (int j = t; j <= NT; j += 1024) h2[j] = h[h[j]];
        __syncthreads();
        for (int j = t; j <= NT; j += 1024) h[j] = h2[j];
        __syncthreads();
    }
    if (t < NT / 32) { wsum[t] = __popc(reach[t]); pref[t] = wsum[t]; }
    __syncthreads();
    for (int off = 1; off < NT / 32; off <<= 1) {
        unsigned v = 0;
        if (t < NT / 32 && t >= off) v = pref[t - off];
        __syncthreads();
        if (t < NT / 32) pref[t] += v;
        __syncthreads();
    }
    int n = pref[NT / 32 - 1];
    for (int j = t; j < NT; j += 1024) {
        unsigned w = reach[j >> 5];
        if (w & (1u << (j & 31))) {
            int r = (int)(pref[j >> 5] - __popc(w) + __popc(w & ((1u << (j & 31)) - 1)));
            start[b * NT + r] = j;
        }
    }
    if (t == 0) { nseg[b] = n; out_tail[b] = (float)n; }
}

// ---------------- Kernel D: means + zeros, wave per row, nontemporal stores --------
__global__ __launch_bounds__(256) void kD_means(const float* __restrict__ in,
                                                const int* __restrict__ nxt,
                                                const int* __restrict__ start,
                                                const int* __restrict__ nseg,
                                                float* __restrict__ out) {
    int wave = blockIdx.x * 4 + (threadIdx.x >> 6);   // 0..65535 = (b, r)
    int lane = threadIdx.x & 63;
    int b = wave >> 12;
    int r = wave & (NT - 1);
    float4 acc0 = make_float4(0.f, 0.f, 0.f, 0.f);
    float4 acc1 = make_float4(0.f, 0.f, 0.f, 0.f);
    int n = nseg[b];
    if (r < n) {
        int s = start[b * NT + r];
        int e = nxt[b * NT + s];
        const float4* base = (const float4*)(in + (size_t)(b * NT + s) * ND);
        int cnt = e - s;
        int f = 0;
        for (; f + 2 <= cnt; f += 2) {
            float4 v0 = base[(size_t)f * (ND / 4) + lane];
            float4 v1 = base[(size_t)f * (ND / 4) + lane + 64];
            float4 w0 = base[(size_t)(f + 1) * (ND / 4) + lane];
            float4 w1 = base[(size_t)(f + 1) * (ND / 4) + lane + 64];
            acc0.x += v0.x + w0.x; acc0.y += v0.y + w0.y;
            acc0.z += v0.z + w0.z; acc0.w += v0.w + w0.w;
            acc1.x += v1.x + w1.x; acc1.y += v1.y + w1.y;
            acc1.z += v1.z + w1.z; acc1.w += v1.w + w1.w;
        }
        if (f < cnt) {
            float4 v0 = base[(size_t)f * (ND / 4) + lane];
            float4 v1 = base[(size_t)f * (ND / 4) + lane + 64];
            acc0.x += v0.x; acc0.y += v0.y; acc0.z += v0.z; acc0.w += v0.w;
            acc1.x += v1.x; acc1.y += v1.y; acc1.z += v1.z; acc1.w += v1.w;
        }
        float c = (float)cnt;
        acc0.x /= c; acc0.y /= c; acc0.z /= c; acc0.w /= c;
        acc1.x /= c; acc1.y /= c; acc1.z /= c; acc1.w /= c;
    }
    // nontemporal: output is never re-read; keep L3 input-resident during kD
    f4v* orow = (f4v*)(out + (size_t)(b * NT + r) * ND);
    f4v o0 = {acc0.x, acc0.y, acc0.z, acc0.w};
    f4v o1 = {acc1.x, acc1.y, acc1.z, acc1.w};
    __builtin_nontemporal_store(o0, &orow[lane]);
    __builtin_nontemporal_store(o1, &orow[lane + 64]);
}

extern "C" void kernel_launch(void* const* d_in, const int* in_sizes, int n_in,
                              void* d_out, int out_size, void* d_ws, size_t ws_size,
                              hipStream_t stream) {
    const float* in = (const float*)d_in[0];
    float* out = (float*)d_out;
    char* ws = (char*)d_ws;

    int* nxt   = (int*)(ws + 0);           // 256 KiB
    int* start = (int*)(ws + 262144);      // 256 KiB
    int* nseg  = (int*)(ws + 524288);      // 64 B

    kA_next <<<16384, 256,  0, stream>>>(in, nxt);
    kChain  <<<NB,    1024, 0, stream>>>(nxt, start, nseg,
                                         out + (size_t)NB * NT * ND);
    kD_means<<<16384, 256,  0, stream>>>(in, nxt, start, nseg, out);
}

// Round 7
// 304.061 us; speedup vs baseline: 1.3810x; 1.3810x over previous
//
#include <hip/hip_runtime.h>

#define NB 16
#define NT 4096
#define ND 512
#define NLEV 12

typedef float f4v __attribute__((ext_vector_type(4)));

// ---------- exact decision path (verified rounds 2-6): f32 diffs, exact f64 sum,
// ---------- round once to f32, compare vs 1024 (== 32^2, monotone w/ sqrtf>32).
__device__ __forceinline__ bool decide_exact(const float* __restrict__ base, int row,
                                             int lane, float4 r0, float4 r1) {
    const float4* fp = (const float4*)(base + (size_t)row * ND);
    float4 y0 = fp[lane];
    float4 y1 = fp[lane + 64];
    float d;
    double sd;
    d = r0.x - y0.x; sd  = (double)d * d;
    d = r0.y - y0.y; sd += (double)d * d;
    d = r0.z - y0.z; sd += (double)d * d;
    d = r0.w - y0.w; sd += (double)d * d;
    d = r1.x - y1.x; sd += (double)d * d;
    d = r1.y - y1.y; sd += (double)d * d;
    d = r1.z - y1.z; sd += (double)d * d;
    d = r1.w - y1.w; sd += (double)d * d;
    #pragma unroll
    for (int off = 32; off >= 1; off >>= 1) sd += __shfl_xor(sd, off, 64);
    return ((float)sd > 1024.0f);
}

// ---------------- Kernel A v7: v5 core (verified 81.5us) + XCD-chunk swizzle --------
// wave per j, 16-lane group per probe, 4 probes/batch, 4 shuffle steps.
// Swizzle: physical block D -> logical L=(D%8)*2048+D/8 so each XCD sweeps a
// contiguous j range; resident window ~2.6MB < 4MB per-XCD L2 -> probe loads L2-hit.
__global__ __launch_bounds__(256) void kA_next(const float* __restrict__ in,
                                               int* __restrict__ nxt) {
    int L = (blockIdx.x & 7) * 2048 + (blockIdx.x >> 3);   // bijective: 16384 = 8*2048
    int wave = L * 4 + (threadIdx.x >> 6);                 // 0..65535 = (b, j)
    int lane = threadIdx.x & 63;
    int b = wave >> 12;
    int j = wave & (NT - 1);
    int g = lane >> 4;    // probe group 0..3
    int q = lane & 15;    // lane within group

    const float* base = in + (size_t)b * NT * ND;
    const float4* jrow = (const float4*)(base + (size_t)j * ND);
    float4 rep[8];
    #pragma unroll
    for (int k = 0; k < 8; ++k) rep[k] = jrow[q + 16 * k];

    int result = NT;
    int i = j + 1;
    while (i < NT) {
        int row = i + g;
        bool valid = row < NT;
        int rc = valid ? row : NT - 1;
        const float4* pr = (const float4*)(base + (size_t)rc * ND);
        float s = 0.f;
        #pragma unroll
        for (int k = 0; k < 8; ++k) {
            float4 x = pr[q + 16 * k];
            float d;
            d = rep[k].x - x.x; s = fmaf(d, d, s);
            d = rep[k].y - x.y; s = fmaf(d, d, s);
            d = rep[k].z - x.z; s = fmaf(d, d, s);
            d = rep[k].w - x.w; s = fmaf(d, d, s);
        }
        s += __shfl_xor(s, 1, 64);
        s += __shfl_xor(s, 2, 64);
        s += __shfl_xor(s, 4, 64);
        s += __shfl_xor(s, 8, 64);

        unsigned long long ym = __ballot(q == 0 && valid && s > 1024.25f);
        unsigned long long am = __ballot(q == 0 && valid && s > 1023.75f && s <= 1024.25f);
        unsigned vy = (unsigned)((ym & 1ull) | ((ym >> 15) & 2ull) |
                                 ((ym >> 30) & 4ull) | ((ym >> 45) & 8ull));
        unsigned va = (unsigned)((am & 1ull) | ((am >> 15) & 2ull) |
                                 ((am >> 30) & 4ull) | ((am >> 45) & 8ull));
        int found = -1;
        for (;;) {   // wave-uniform resolve in ascending probe order
            int gy = vy ? (__ffs(vy) - 1) : 4;
            int ga = va ? (__ffs(va) - 1) : 4;
            if (ga < gy) {
                float4 r0 = jrow[lane];        // rare path; L1-hot reload
                float4 r1 = jrow[lane + 64];
                if (decide_exact(base, i + ga, lane, r0, r1)) { found = i + ga; break; }
                va &= va - 1;
            } else {
                if (gy < 4) found = i + gy;
                break;
            }
        }
        if (found >= 0) { result = found; break; }
        i += 4;
    }
    if (lane == 0) nxt[b * NT + j] = result;
}

// ---------------- kChain v2: doubling + PER-BIT-PARALLEL closure --------------------
// Closure now uses all 1024 threads (4 bits each) instead of 128 threads walking
// set bits serially. Monotone: seeing later-set bits only accelerates convergence.
__global__ __launch_bounds__(1024) void kChain(const int* __restrict__ nxt,
                                               int* __restrict__ start,
                                               int* __restrict__ nseg,
                                               float* __restrict__ out_tail) {
    __shared__ unsigned short h[NT + 1];
    __shared__ unsigned short h2[NT + 1];
    __shared__ unsigned reach[NT / 32];
    __shared__ unsigned pref[NT / 32];
    int b = blockIdx.x;
    int t = threadIdx.x;
    for (int j = t; j <= NT; j += 1024)
        h[j] = (j < NT) ? (unsigned short)nxt[b * NT + j] : (unsigned short)NT;
    for (int w = t; w < NT / 32; w += 1024) reach[w] = 0;
    __syncthreads();
    if (t == 0) reach[0] = 1u;
    __syncthreads();
    for (int k = 0; k < NLEV; ++k) {
        // R |= h(R): bit-parallel over all 4096 positions
        #pragma unroll
        for (int j = t; j < NT; j += 1024) {
            if (reach[j >> 5] & (1u << (j & 31))) {
                int d = h[j];
                if (d < NT) atomicOr(&reach[d >> 5], 1u << (d & 31));
            }
        }
        __syncthreads();
        for (int j = t; j <= NT; j += 1024) h2[j] = h[h[j]];
        __syncthreads();
        for (int j = t; j <= NT; j += 1024) h[j] = h2[j];
        __syncthreads();
    }
    if (t < NT / 32) pref[t] = __popc(reach[t]);
    __syncthreads();
    for (int off = 1; off < NT / 32; off <<= 1) {
        unsigned v = 0;
        if (t < NT / 32 && t >= off) v = pref[t - off];
        __syncthreads();
        if (t < NT / 32) pref[t] += v;
        __syncthreads();
    }
    int n = pref[NT / 32 - 1];
    for (int j = t; j < NT; j += 1024) {
        unsigned w = reach[j >> 5];
        if (w & (1u << (j & 31))) {
            int r = (int)(pref[j >> 5] - __popc(w) + __popc(w & ((1u << (j & 31)) - 1)));
            start[b * NT + r] = j;
        }
    }
    if (t == 0) { nseg[b] = n; out_tail[b] = (float)n; }
}

// ---------------- Kernel D: means + zeros, wave per row, nt stores (verified) ------
__global__ __launch_bounds__(256) void kD_means(const float* __restrict__ in,
                                                const int* __restrict__ nxt,
                                                const int* __restrict__ start,
                                                const int* __restrict__ nseg,
                                                float* __restrict__ out) {
    int wave = blockIdx.x * 4 + (threadIdx.x >> 6);   // 0..65535 = (b, r)
    int lane = threadIdx.x & 63;
    int b = wave >> 12;
    int r = wave & (NT - 1);
    float4 acc0 = make_float4(0.f, 0.f, 0.f, 0.f);
    float4 acc1 = make_float4(0.f, 0.f, 0.f, 0.f);
    int n = nseg[b];
    if (r < n) {
        int s = start[b * NT + r];
        int e = nxt[b * NT + s];
        const float4* base = (const float4*)(in + (size_t)(b * NT + s) * ND);
        int cnt = e - s;
        int f = 0;
        for (; f + 2 <= cnt; f += 2) {
            float4 v0 = base[(size_t)f * (ND / 4) + lane];
            float4 v1 = base[(size_t)f * (ND / 4) + lane + 64];
            float4 w0 = base[(size_t)(f + 1) * (ND / 4) + lane];
            float4 w1 = base[(size_t)(f + 1) * (ND / 4) + lane + 64];
            acc0.x += v0.x + w0.x; acc0.y += v0.y + w0.y;
            acc0.z += v0.z + w0.z; acc0.w += v0.w + w0.w;
            acc1.x += v1.x + w1.x; acc1.y += v1.y + w1.y;
            acc1.z += v1.z + w1.z; acc1.w += v1.w + w1.w;
        }
        if (f < cnt) {
            float4 v0 = base[(size_t)f * (ND / 4) + lane];
            float4 v1 = base[(size_t)f * (ND / 4) + lane + 64];
            acc0.x += v0.x; acc0.y += v0.y; acc0.z += v0.z; acc0.w += v0.w;
            acc1.x += v1.x; acc1.y += v1.y; acc1.z += v1.z; acc1.w += v1.w;
        }
        float c = (float)cnt;
        acc0.x /= c; acc0.y /= c; acc0.z /= c; acc0.w /= c;
        acc1.x /= c; acc1.y /= c; acc1.z /= c; acc1.w /= c;
    }
    f4v* orow = (f4v*)(out + (size_t)(b * NT + r) * ND);
    f4v o0 = {acc0.x, acc0.y, acc0.z, acc0.w};
    f4v o1 = {acc1.x, acc1.y, acc1.z, acc1.w};
    __builtin_nontemporal_store(o0, &orow[lane]);
    __builtin_nontemporal_store(o1, &orow[lane + 64]);
}

extern "C" void kernel_launch(void* const* d_in, const int* in_sizes, int n_in,
                              void* d_out, int out_size, void* d_ws, size_t ws_size,
                              hipStream_t stream) {
    const float* in = (const float*)d_in[0];
    float* out = (float*)d_out;
    char* ws = (char*)d_ws;

    int* nxt   = (int*)(ws + 0);           // 256 KiB
    int* start = (int*)(ws + 262144);      // 256 KiB
    int* nseg  = (int*)(ws + 524288);      // 64 B

    kA_next <<<16384, 256,  0, stream>>>(in, nxt);
    kChain  <<<NB,    1024, 0, stream>>>(nxt, start, nseg,
                                         out + (size_t)NB * NT * ND);
    kD_means<<<16384, 256,  0, stream>>>(in, nxt, start, nseg, out);
}